// Round 3
// baseline (6277.725 us; speedup 1.0000x reference)
//
#include <hip/hip_runtime.h>
#include <hip/hip_bf16.h>
#include <math.h>

// ---- problem constants ----
#define NL 26
#define TT 16
#define DD 768
#define HDD 128
#define FFF 3072
#define VV 32000
#define SCCH 4096
#define STOT 4112      // SC + T
#define OQKV 1536      // NG*(G+2)*HD
#define EPSF 1e-6f
#define SCALEQ 0.08838834764831845f  // 1/sqrt(128)

// ---------- helpers ----------
__device__ __forceinline__ float d4(const float4 a, const float4 b) {
    return fmaf(a.x, b.x, fmaf(a.y, b.y, fmaf(a.z, b.z, a.w * b.w)));
}
__device__ __forceinline__ float4 f4add4(float4 a, float4 b, float4 c, float4 d) {
    return make_float4((a.x + b.x) + (c.x + d.x), (a.y + b.y) + (c.y + d.y),
                       (a.z + b.z) + (c.z + d.z), (a.w + b.w) + (c.w + d.w));
}
// h + f*s*(1+w)
__device__ __forceinline__ float4 f4res(float4 h, float4 f, float s, float4 w) {
    return make_float4(fmaf(f.x * s, 1.f + w.x, h.x), fmaf(f.y * s, 1.f + w.y, h.y),
                       fmaf(f.z * s, 1.f + w.z, h.z), fmaf(f.w * s, 1.f + w.w, h.w));
}
// h*s*(1+w)
__device__ __forceinline__ float4 f4nrm(float4 h, float s, float4 w) {
    return make_float4(h.x * s * (1.f + w.x), h.y * s * (1.f + w.y),
                       h.z * s * (1.f + w.z), h.w * s * (1.f + w.w));
}
__device__ __forceinline__ float r16(float v) {
    v += __shfl_xor(v, 1); v += __shfl_xor(v, 2); v += __shfl_xor(v, 4); v += __shfl_xor(v, 8);
    return v;
}
__device__ __forceinline__ float rwave(float v) {
    v += __shfl_xor(v, 32); v += __shfl_xor(v, 16); v += __shfl_xor(v, 8);
    v += __shfl_xor(v, 4);  v += __shfl_xor(v, 2);  v += __shfl_xor(v, 1);
    return v;
}

// GEMV inner: one weight row (K4 float4s) vs 16 token vectors (LDS or global).
template <int K4>
__device__ __forceinline__ void gemv_row(const float4* __restrict__ w4,
                                         const float* __restrict__ xs, int lane,
                                         float* __restrict__ acc) {
#pragma unroll
    for (int t = 0; t < TT; t++) acc[t] = 0.f;
    const float4* x4 = reinterpret_cast<const float4*>(xs);
#pragma unroll
    for (int it = 0; it < K4 / 64; ++it) {
        float4 w = w4[it * 64 + lane];
#pragma unroll
        for (int t = 0; t < TT; t++) {
            float4 x = x4[t * K4 + it * 64 + lane];
            acc[t] = fmaf(w.x, x.x, fmaf(w.y, x.y, fmaf(w.z, x.z, fmaf(w.w, x.w, acc[t]))));
        }
    }
#pragma unroll
    for (int t = 0; t < TT; t++) acc[t] = rwave(acc[t]);
}

// ---------- K1: (deferred ff residual) + pre-attn rmsnorm + QKV GEMV ----------
__global__ __launch_bounds__(256) void k_qkv(const int first,
                                             const float* __restrict__ hB,
                                             const float* __restrict__ ff,   // [4][16][768]
                                             const float* __restrict__ emb,
                                             const float* __restrict__ pofn_prev,
                                             const float* __restrict__ pan,
                                             const float* __restrict__ W,    // [1536][768]
                                             float* __restrict__ qkvo,       // [16][1536]
                                             float* __restrict__ hA) {
    __shared__ __align__(16) float xs[TT * DD];
    const int tid = threadIdx.x;
    const int row = tid >> 4, c16 = tid & 15;
    float4* xr = reinterpret_cast<float4*>(xs) + row * 192;
    float4* hA4 = reinterpret_cast<float4*>(hA) + row * 192;
    if (first) {
        const float4* e4 = reinterpret_cast<const float4*>(emb) + row * 192;
        float ss = 0.f;
#pragma unroll
        for (int k = 0; k < 12; k++) { int i = c16 + 16 * k; float4 v = e4[i]; xr[i] = v; ss += d4(v, v); }
        ss = r16(ss);
        float inv = rsqrtf(ss * (1.f / 768.f) + EPSF);
        if (blockIdx.x == 0) {
#pragma unroll
            for (int k = 0; k < 12; k++) { int i = c16 + 16 * k; hA4[i] = xr[i]; }
        }
        const float4* p4 = reinterpret_cast<const float4*>(pan);
#pragma unroll
        for (int k = 0; k < 12; k++) { int i = c16 + 16 * k; xr[i] = f4nrm(xr[i], inv, p4[i]); }
    } else {
        const float4* f0 = reinterpret_cast<const float4*>(ff) + row * 192;
        const float4* f1 = f0 + TT * 192;
        const float4* f2 = f1 + TT * 192;
        const float4* f3 = f2 + TT * 192;
        float ss = 0.f;
#pragma unroll
        for (int k = 0; k < 12; k++) {
            int i = c16 + 16 * k;
            float4 v = f4add4(f0[i], f1[i], f2[i], f3[i]);
            xr[i] = v; ss += d4(v, v);
        }
        ss = r16(ss);
        float inv = rsqrtf(ss * (1.f / 768.f) + EPSF);
        const float4* hb4 = reinterpret_cast<const float4*>(hB) + row * 192;
        const float4* po4 = reinterpret_cast<const float4*>(pofn_prev);
        float ss2 = 0.f;
#pragma unroll
        for (int k = 0; k < 12; k++) {
            int i = c16 + 16 * k;
            float4 v = f4res(hb4[i], xr[i], inv, po4[i]);
            xr[i] = v; ss2 += d4(v, v);
            if (blockIdx.x == 0) hA4[i] = v;
        }
        ss2 = r16(ss2);
        float inv2 = rsqrtf(ss2 * (1.f / 768.f) + EPSF);
        const float4* p4 = reinterpret_cast<const float4*>(pan);
#pragma unroll
        for (int k = 0; k < 12; k++) { int i = c16 + 16 * k; xr[i] = f4nrm(xr[i], inv2, p4[i]); }
    }
    __syncthreads();
    const int wv = tid >> 6, lane = tid & 63;
#pragma unroll
    for (int rr = 0; rr < 2; ++rr) {
        const int o = blockIdx.x * 8 + rr * 4 + wv;
        float acc[TT];
        gemv_row<192>(reinterpret_cast<const float4*>(W + (size_t)o * DD), xs, lane, acc);
        if (lane < TT) qkvo[lane * OQKV + o] = acc[lane];
    }
}

// ---------- K2a: new-token K (norm+rope) and V; f32 to ws and to outputs ----------
// grid (NG=2, T=16), block 64.
__global__ __launch_bounds__(64) void k_kvnew(const float* __restrict__ qkv,
                                              const float* __restrict__ cosp,
                                              const float* __restrict__ sinp,
                                              const float* __restrict__ knw,
                                              float* __restrict__ knew,   // [2][16][128]
                                              float* __restrict__ vnew,   // [2][128][16]
                                              float* __restrict__ kout,
                                              float* __restrict__ vout) {
    const int ng = blockIdx.x, t = blockIdx.y, lane = threadIdx.x;
    const float* srck = qkv + t * OQKV + ng * 768 + 4 * 128;
    float a = srck[lane], b = srck[lane + 64];
    float ss = rwave(a * a + b * b);
    float inv = rsqrtf(ss * (1.f / 128.f) + EPSF);
    float an = a * inv * (1.f + knw[lane]);
    float bn = b * inv * (1.f + knw[lane + 64]);
    float o0 = an * cosp[t * 128 + lane]      - bn * sinp[t * 128 + lane];
    float o1 = bn * cosp[t * 128 + lane + 64] + an * sinp[t * 128 + lane + 64];
    int kb = (ng * TT + t) * 128;
    knew[kb + lane] = o0; knew[kb + lane + 64] = o1;
    kout[kb + lane] = o0; kout[kb + lane + 64] = o1;
    const float* srcv = qkv + t * OQKV + ng * 768 + 5 * 128;
    float v0 = srcv[lane], v1 = srcv[lane + 64];
    vnew[(ng * 128 + lane) * TT + t] = v0;
    vnew[(ng * 128 + lane + 64) * TT + t] = v1;
    vout[(ng * 128 + lane) * TT + t] = v0;
    vout[(ng * 128 + lane + 64) * TT + t] = v1;
}

// ---------- K2b: exact attention, one block per (q-row, group) ----------
// grid (64, 2), block 256. Full 4112-wide score row in LDS.
__global__ __launch_bounds__(256) void k_attn2(const float* __restrict__ qkv,
                                               const float* __restrict__ kc,   // [2][4096][128]
                                               const float* __restrict__ vc,   // [2][128][4096]
                                               const float* __restrict__ knew, // [2][16][128]
                                               const float* __restrict__ vnew, // [2][128][16]
                                               const float* __restrict__ cosp,
                                               const float* __restrict__ sinp,
                                               const float* __restrict__ mask, // [16][4112]
                                               const float* __restrict__ qnw,
                                               float* __restrict__ attn) {     // [16][1024]
    __shared__ __align__(16) float ps[STOT];
    __shared__ __align__(16) float qs[128];
    __shared__ float wred[8];
    const int tid = threadIdx.x;
    const int r = blockIdx.x, ng = blockIdx.y;
    const int tsrc = r >> 2, g = r & 3, pos = r & 15;
    if (tid < 64) {
        const float* src = qkv + tsrc * OQKV + ng * 768 + g * 128;
        float a = src[tid], b = src[tid + 64];
        float ss = rwave(a * a + b * b);
        float inv = rsqrtf(ss * (1.f / 128.f) + EPSF);
        float an = a * inv * (1.f + qnw[tid]);
        float bn = b * inv * (1.f + qnw[tid + 64]);
        qs[tid]      = an * cosp[pos * 128 + tid]      - bn * sinp[pos * 128 + tid];
        qs[tid + 64] = bn * cosp[pos * 128 + tid + 64] + an * sinp[pos * 128 + tid + 64];
    }
    __syncthreads();
    const float4* q4 = reinterpret_cast<const float4*>(qs);
    const float* mrow = mask + pos * STOT;
    float mx = -1e30f;
    for (int s = tid; s < STOT; s += 256) {
        const float4* k4 = (s < SCCH)
            ? reinterpret_cast<const float4*>(kc + (size_t)(ng * SCCH + s) * 128)
            : reinterpret_cast<const float4*>(knew + (size_t)(ng * TT + (s - SCCH)) * 128);
        float p = 0.f;
#pragma unroll
        for (int i = 0; i < 32; i++) p += d4(q4[i], k4[i]);
        p *= SCALEQ;
        p = 50.f * tanhf(p * 0.02f);
        p += mrow[s];
        ps[s] = p;
        mx = fmaxf(mx, p);
    }
    mx = fmaxf(mx, __shfl_xor(mx, 32)); mx = fmaxf(mx, __shfl_xor(mx, 16));
    mx = fmaxf(mx, __shfl_xor(mx, 8));  mx = fmaxf(mx, __shfl_xor(mx, 4));
    mx = fmaxf(mx, __shfl_xor(mx, 2));  mx = fmaxf(mx, __shfl_xor(mx, 1));
    if ((tid & 63) == 0) wred[tid >> 6] = mx;
    __syncthreads();
    const float M = fmaxf(fmaxf(wred[0], wred[1]), fmaxf(wred[2], wred[3]));
    float ls = 0.f;
    for (int s = tid; s < STOT; s += 256) {
        float p = expf(ps[s] - M);
        ps[s] = p;
        ls += p;
    }
    ls = rwave(ls);
    if ((tid & 63) == 0) wred[4 + (tid >> 6)] = ls;
    __syncthreads();
    const float L = (wred[4] + wred[5]) + (wred[6] + wred[7]);
    // PV: d = tid>>1, s-half = tid&1
    const int d = tid >> 1, half = tid & 1;
    const float4* p4 = reinterpret_cast<const float4*>(ps);
    const float4* v4 = reinterpret_cast<const float4*>(vc + (size_t)(ng * 128 + d) * SCCH);
    float acc = 0.f;
    if (half == 0) {
        for (int i = 0; i < 514; i++) acc += d4(p4[i], v4[i]);
    } else {
        for (int i = 514; i < 1024; i++) acc += d4(p4[i], v4[i]);
        const float4* w4 = reinterpret_cast<const float4*>(vnew + (ng * 128 + d) * TT);
#pragma unroll
        for (int i = 0; i < 4; i++) acc += d4(p4[1024 + i], w4[i]);
    }
    acc += __shfl_xor(acc, 1);
    if (half == 0) {
        int h = ng * 4 + (r >> 4);
        attn[pos * 1024 + h * 128 + d] = acc / L;
    }
}

// ---------- K4: out projection (reads attn straight from L2; no LDS) ----------
__global__ __launch_bounds__(256) void k_outproj(const float* __restrict__ W, // [768][1024]
                                                 const float* __restrict__ attn,
                                                 float* __restrict__ y) {
    int tid = threadIdx.x;
    int wv = tid >> 6, lane = tid & 63;
#pragma unroll
    for (int rr = 0; rr < 2; ++rr) {
        int o = blockIdx.x * 8 + rr * 4 + wv;
        float acc[TT];
        gemv_row<256>(reinterpret_cast<const float4*>(W + (size_t)o * 1024), attn, lane, acc);
        if (lane < TT) y[lane * DD + o] = acc[lane];
    }
}

// ---------- K5: post-attn residual+norm, pre-ff norm, gate/up GEMV + GELU*up ----------
__global__ __launch_bounds__(256) void k_gateup(const float* __restrict__ hA,
                                                const float* __restrict__ y,
                                                const float* __restrict__ postw,
                                                const float* __restrict__ pfn,
                                                const float* __restrict__ gw,
                                                const float* __restrict__ uw,
                                                float* __restrict__ act,
                                                float* __restrict__ hB) {
    __shared__ __align__(16) float xs[TT * DD];
    int tid = threadIdx.x;
    int row = tid >> 4, c16 = tid & 15;
    float4* xr = reinterpret_cast<float4*>(xs) + row * 192;
    const float4* y4 = reinterpret_cast<const float4*>(y) + row * 192;
    float ss = 0.f;
#pragma unroll
    for (int k = 0; k < 12; k++) { int i = c16 + 16 * k; float4 v = y4[i]; xr[i] = v; ss += d4(v, v); }
    ss = r16(ss);
    float inv = rsqrtf(ss * (1.f / 768.f) + EPSF);
    const float4* ha4 = reinterpret_cast<const float4*>(hA) + row * 192;
    const float4* pw4 = reinterpret_cast<const float4*>(postw);
    float4* hB4 = reinterpret_cast<float4*>(hB) + row * 192;
    float ss2 = 0.f;
#pragma unroll
    for (int k = 0; k < 12; k++) {
        int i = c16 + 16 * k;
        float4 v = f4res(ha4[i], xr[i], inv, pw4[i]);
        xr[i] = v; ss2 += d4(v, v);
        if (blockIdx.x == 0) hB4[i] = v;
    }
    ss2 = r16(ss2);
    float inv2 = rsqrtf(ss2 * (1.f / 768.f) + EPSF);
    const float4* pf4 = reinterpret_cast<const float4*>(pfn);
#pragma unroll
    for (int k = 0; k < 12; k++) { int i = c16 + 16 * k; xr[i] = f4nrm(xr[i], inv2, pf4[i]); }
    __syncthreads();
    int wv = tid >> 6, lane = tid & 63;
#pragma unroll
    for (int rr = 0; rr < 2; ++rr) {
        int f = blockIdx.x * 8 + rr * 4 + wv;
        float ag[TT], au[TT];
        gemv_row<192>(reinterpret_cast<const float4*>(gw + (size_t)f * DD), xs, lane, ag);
        gemv_row<192>(reinterpret_cast<const float4*>(uw + (size_t)f * DD), xs, lane, au);
        if (lane < TT) {
            float g = ag[lane], u = au[lane];
            float inner = 0.7978845608028654f * fmaf(0.044715f * g, g * g, g);
            float gel = 0.5f * g * (1.f + tanhf(inner));
            act[lane * FFF + f] = gel * u;
        }
    }
}

// ---------- K6: down GEMV in f-quarters -> ff partials [4][16][768] ----------
__global__ __launch_bounds__(256) void k_down(const float* __restrict__ W, // [768][3072]
                                              const float* __restrict__ act,
                                              float* __restrict__ ffp) {
    __shared__ __align__(16) float xs[TT * DD];
    int tid = threadIdx.x;
    int fq = blockIdx.x & 3, dc = blockIdx.x >> 2;
    {
        const float4* a4 = reinterpret_cast<const float4*>(act);
        float4* s4 = reinterpret_cast<float4*>(xs);
#pragma unroll
        for (int k = 0; k < 12; k++) {
            int i = tid + 256 * k;
            int t = i / 192, cq = i - t * 192;
            s4[i] = a4[t * 768 + fq * 192 + cq];
        }
    }
    __syncthreads();
    int wv = tid >> 6, lane = tid & 63;
#pragma unroll
    for (int rr = 0; rr < 2; ++rr) {
        int o = dc * 8 + rr * 4 + wv;
        float acc[TT];
        gemv_row<192>(reinterpret_cast<const float4*>(W + (size_t)o * FFF + fq * 768), xs, lane, acc);
        if (lane < TT) ffp[(fq * TT + lane) * DD + o] = acc[lane];
    }
}

// ---------- final x ----------
__global__ void k_finalx(const float* __restrict__ hB, const float* __restrict__ ff,
                         const float* __restrict__ pofn, const float* __restrict__ fnw,
                         float* __restrict__ xfin) {
    int t = blockIdx.x, lane = threadIdx.x;
    const float4* h4 = reinterpret_cast<const float4*>(hB) + t * 192;
    const float4* f0 = reinterpret_cast<const float4*>(ff) + t * 192;
    const float4* f1 = f0 + TT * 192;
    const float4* f2 = f1 + TT * 192;
    const float4* f3 = f2 + TT * 192;
    float4 vals[3];
    float ss = 0.f;
#pragma unroll
    for (int k = 0; k < 3; k++) {
        int i = lane + 64 * k;
        float4 s = f4add4(f0[i], f1[i], f2[i], f3[i]);
        vals[k] = s; ss += d4(s, s);
    }
    ss = rwave(ss);
    float inv = rsqrtf(ss * (1.f / 768.f) + EPSF);
    const float4* po4 = reinterpret_cast<const float4*>(pofn);
    float ss2 = 0.f;
#pragma unroll
    for (int k = 0; k < 3; k++) {
        int i = lane + 64 * k;
        float4 v = f4res(h4[i], vals[k], inv, po4[i]);
        vals[k] = v; ss2 += d4(v, v);
    }
    ss2 = rwave(ss2);
    float inv2 = rsqrtf(ss2 * (1.f / 768.f) + EPSF);
    const float4* fn4 = reinterpret_cast<const float4*>(fnw);
    float4* xf4 = reinterpret_cast<float4*>(xfin) + t * 192;
#pragma unroll
    for (int k = 0; k < 3; k++) {
        int i = lane + 64 * k;
        xf4[i] = f4nrm(vals[k], inv2, fn4[i]);
    }
}

// ---------- lm_head: logits (f32) ----------
__global__ __launch_bounds__(256) void k_lmhead(const float* __restrict__ xfin,
                                                const float* __restrict__ W, // [32000][768]
                                                float* __restrict__ logits) {
    __shared__ __align__(16) float xs[TT * DD];
    int tid = threadIdx.x;
    {
        const float4* x4 = reinterpret_cast<const float4*>(xfin);
        float4* s4 = reinterpret_cast<float4*>(xs);
#pragma unroll
        for (int k = 0; k < 12; k++) s4[tid + 256 * k] = x4[tid + 256 * k];
    }
    __syncthreads();
    int wv = tid >> 6, lane = tid & 63;
#pragma unroll
    for (int rr = 0; rr < 4; ++rr) {
        int o = blockIdx.x * 16 + rr * 4 + wv;
        float acc[TT];
        gemv_row<192>(reinterpret_cast<const float4*>(W + (size_t)o * DD), xs, lane, acc);
        if (lane < TT) logits[lane * VV + o] = acc[lane];
    }
}

extern "C" void kernel_launch(void* const* d_in, const int* in_sizes, int n_in,
                              void* d_out, int out_size, void* d_ws, size_t ws_size,
                              hipStream_t stream) {
    const float* emb   = (const float*)d_in[0];
    const float* maskg = (const float*)d_in[1];
    const float* maskl = (const float*)d_in[2];
    const float* cosg  = (const float*)d_in[3];
    const float* sing  = (const float*)d_in[4];
    const float* cosl  = (const float*)d_in[5];
    const float* sinl  = (const float*)d_in[6];
    const float* kck   = (const float*)d_in[7];
    const float* kcv   = (const float*)d_in[8];
    const float* pan   = (const float*)d_in[9];
    const float* qkvw  = (const float*)d_in[10];
    const float* qnw   = (const float*)d_in[11];
    const float* knw   = (const float*)d_in[12];
    const float* outw  = (const float*)d_in[13];
    const float* postw = (const float*)d_in[14];
    const float* pfnw  = (const float*)d_in[15];
    const float* gw    = (const float*)d_in[16];
    const float* uw    = (const float*)d_in[17];
    const float* dw    = (const float*)d_in[18];
    const float* pofn  = (const float*)d_in[19];
    const float* fnw   = (const float*)d_in[20];
    const float* lmw   = (const float*)d_in[21];

    float* ws   = (float*)d_ws;
    float* hA   = ws;                 // 12288
    float* hB   = hA + 12288;         // 12288
    float* qkv  = hB + 12288;         // 24576
    float* attn = qkv + 24576;        // 16384
    float* yb   = attn + 16384;       // 12288
    float* act  = yb + 12288;         // 49152
    float* ffp  = act + 49152;        // 49152
    float* knew = ffp + 49152;        // 4096
    float* vnew = knew + 4096;        // 4096
    float* xfin = vnew + 4096;        // 12288

    float* outp = (float*)d_out;
    float* outK = outp + 512000;
    float* outV = outK + 106496;

    for (int l = 0; l < NL; l++) {
        int loc = ((l + 1) % 6) == 0;
        const float* cosp = loc ? cosl : cosg;
        const float* sinp = loc ? sinl : sing;
        const float* maskp = loc ? maskl : maskg;
        k_qkv<<<192, 256, 0, stream>>>(l == 0 ? 1 : 0, hB, ffp, emb,
                                       l ? (pofn + (size_t)(l - 1) * DD) : pofn,
                                       pan + (size_t)l * DD,
                                       qkvw + (size_t)l * OQKV * DD, qkv, hA);
        k_kvnew<<<dim3(2, TT), 64, 0, stream>>>(qkv, cosp, sinp, knw + (size_t)l * HDD,
                                                knew, vnew,
                                                outK + (size_t)l * 2 * TT * HDD,
                                                outV + (size_t)l * 2 * HDD * TT);
        k_attn2<<<dim3(64, 2), 256, 0, stream>>>(qkv,
                                                 kck + (size_t)l * 2 * SCCH * HDD,
                                                 kcv + (size_t)l * 2 * HDD * SCCH,
                                                 knew, vnew, cosp, sinp, maskp,
                                                 qnw + (size_t)l * HDD, attn);
        k_outproj<<<96, 256, 0, stream>>>(outw + (size_t)l * DD * 1024, attn, yb);
        k_gateup<<<384, 256, 0, stream>>>(hA, yb, postw + (size_t)l * DD, pfnw + (size_t)l * DD,
                                          gw + (size_t)l * FFF * DD, uw + (size_t)l * FFF * DD,
                                          act, hB);
        k_down<<<384, 256, 0, stream>>>(dw + (size_t)l * DD * FFF, act, ffp);
    }
    k_finalx<<<16, 64, 0, stream>>>(hB, ffp, pofn + (size_t)25 * DD, fnw, xfin);
    k_lmhead<<<2000, 256, 0, stream>>>(xfin, lmw, outp);
}